// Round 4
// baseline (294.403 us; speedup 1.0000x reference)
//
#include <hip/hip_runtime.h>
#include <math.h>

// Problem geometry (fixed by the reference).
#define BB 32
#define TT 65536
#define MAXSEG 256             // onsets/row ~ Binom(65536,5e-4) = 33±6 -> P(>=256) ~ 0
#define CHUNK 8                // samples per scan chunk (1 chunk per thread)
#define SPB 2048               // samples per phase block = 256 threads * CHUNK
#define NBLK (BB * TT / SPB)   // 1024 phase blocks (32 per row)
#define CPR (TT / CHUNK)       // 8192 chunks per row
#define NCHUNKS (BB * CPR)     // 262144
#define NGROUPS (NCHUNKS / 64) // 4096 (64-chunk groups == one wave each)
#define HALO 448               // comb reach: zi<=399 -> i2 >= t-401; +2 carry-in -> <=403

// map_logspace constants: lo * (hi/lo)^sig = lo * exp(sig*ln(hi/lo))
#define MIN_W_C 0.007853981633974483f  // 2*pi*20/16000
#define LNW 5.991464547107982f         // ln(400)
#define MIN_Q_C 0.5f
#define LNQ 1.3862943611198906f        // ln(4)
#define MIN_D_C 0.1f
#define LND 2.995732273553991f         // ln(20)

__device__ __forceinline__ int SK(int i)  { return i + (i >> 5); }  // float-LDS skew
__device__ __forceinline__ int SKB(int i) { return i + (i >> 4); }  // byte-LDS skew
__device__ __forceinline__ float sigmoidf_(float x) { return 1.0f / (1.0f + expf(-x)); }

// ---------- K1a: per-256-sample-block onset counts (coalesced int4, wave-reduce) ----------
__global__ __launch_bounds__(256) void k_count(const int* __restrict__ onsets,
                                               int* __restrict__ bsum) {
    int tid = threadIdx.x;
    int gid = blockIdx.x * 256 + tid;                 // 2048 blocks; int4 per thread
    int4 v = ((const int4*)onsets)[gid];
    int c = v.x + v.y + v.z + v.w;
    for (int off = 32; off; off >>= 1) c += __shfl_xor(c, off);
    if ((tid & 63) == 0) bsum[blockIdx.x * 4 + (tid >> 6)] = c;  // wave covers 256 samples
}

// ---------- K1b: per-row exclusive prefix of the 256 block-counts ----------
__global__ __launch_bounds__(64) void k_rowpre(const int* __restrict__ bsum,
                                               int* __restrict__ bpre) {
    int r = blockIdx.x, l = threadIdx.x;
    int acc = 0;
    for (int g = 0; g < 4; ++g) {
        int v = bsum[r * 256 + g * 64 + l];
        int x = v;
        for (int off = 1; off < 64; off <<= 1) { int y = __shfl_up(x, off); if (l >= off) x += y; }
        bpre[r * 256 + g * 64 + l] = acc + x - v;     // exclusive
        acc += __shfl(x, 63);
    }
}

// ---------- K1c: seg assignment (1 sample/thread) + wave-aggregated segment sums ----------
__global__ __launch_bounds__(256) void k_assign(const int* __restrict__ onsets,
                                                const float* __restrict__ params,
                                                const int* __restrict__ bpre,
                                                unsigned char* __restrict__ seg,
                                                float* __restrict__ sums,   // [BB][256][4]
                                                float* __restrict__ cnt) {  // [BB][256]
    int blk = blockIdx.x;                 // 8192 blocks, 256 samples each (256/row)
    int tid = threadIdx.x;
    int row = blk >> 8;
    size_t g = ((size_t)blk << 8) + tid;
    int lane = tid & 63, w = tid >> 6;

    int on = onsets[g];
    int x = on;
    for (int off = 1; off < 64; off <<= 1) { int y = __shfl_up(x, off); if (lane >= off) x += y; }
    __shared__ int wt[4];
    if (lane == 63) wt[w] = x;
    __syncthreads();
    int wadd = 0;
    for (int i = 0; i < w; ++i) wadd += wt[i];
    int incl = bpre[blk] + wadd + x;      // inclusive cumsum of onsets at this sample
    int s = min(incl, MAXSEG - 1);
    seg[g] = (unsigned char)s;

    float4 pv = ((const float4*)params)[g];
    float* sums_b = sums + ((size_t)row << 10);
    float* cnt_b  = cnt  + ((size_t)row << 8);
    int sf = __shfl(s, 0);
    if (__all(s == sf)) {                 // wave-uniform segment (~97% of waves)
        float a0 = pv.x, a1 = pv.y, a2 = pv.z, a3 = pv.w;
        for (int off = 32; off; off >>= 1) {
            a0 += __shfl_xor(a0, off); a1 += __shfl_xor(a1, off);
            a2 += __shfl_xor(a2, off); a3 += __shfl_xor(a3, off);
        }
        if (lane == 0) {
            atomicAdd(&sums_b[s * 4 + 0], a0);
            atomicAdd(&sums_b[s * 4 + 1], a1);
            atomicAdd(&sums_b[s * 4 + 2], a2);
            atomicAdd(&sums_b[s * 4 + 3], a3);
            atomicAdd(&cnt_b[s], 64.0f);
        }
    } else {
        atomicAdd(&sums_b[s * 4 + 0], pv.x);
        atomicAdd(&sums_b[s * 4 + 1], pv.y);
        atomicAdd(&sums_b[s * 4 + 2], pv.z);
        atomicAdd(&sums_b[s * 4 + 3], pv.w);
        atomicAdd(&cnt_b[s], 1.0f);
    }
}

// ---------- K1d: per-(row,segment) coefficient table {dist, mu, b0, b1, ca1, ca2, -, -} ----------
__global__ __launch_bounds__(256) void k_coefs(const float* __restrict__ sums,
                                               const float* __restrict__ cnt,
                                               float* __restrict__ coef) {
    int idx = blockIdx.x * 256 + threadIdx.x;   // < 8192
    float c = fmaxf(cnt[idx], 1.0f);
    const float* sb = sums + (size_t)idx * 4;
    float p0 = sb[0] / c, p1 = sb[1] / c, p2 = sb[2] / c, p3 = sb[3] / c;
    float dist = MIN_D_C * expf(sigmoidf_(p0) * LND);
    float mu   = sigmoidf_(p3);
    float wq   = MIN_W_C * expf(sigmoidf_(p1) * LNW);
    float q    = MIN_Q_C * expf(sigmoidf_(p2) * LNQ);
    float cw = cosf(wq), sn = sinf(wq);
    float al = sn / (2.0f * q);
    float a0 = 1.0f + al;
    float omc = 1.0f - cw;
    float b0 = omc * 0.5f / a0;
    float b1 = omc / a0;
    float ca1 = (-2.0f * cw) / a0;
    float ca2 = (1.0f - al) / a0;
    float4* o = (float4*)(coef + (size_t)idx * 8);
    o[0] = make_float4(dist, mu, b0, b1);
    o[1] = make_float4(ca1, ca2, 0.0f, 0.0f);
}

// ---------- shared helpers for the phase kernels ----------
// comb output at local index lt (lt may be negative, >= -HALO+403); dist applied on the fly
__device__ __forceinline__ float comb_lds(const float* __restrict__ in_l,
                                          const unsigned char* __restrict__ seg_l,
                                          const float* __restrict__ dist_l,
                                          float f0v, float mu, int lt) {
    float p = f0v * mu;                 // in (0, 400)
    int zi = (int)p;
    float alfa = p - (float)zi;
    int i1 = lt - zi - 1;
    float x0 = in_l[SK(HALO + lt)]     * dist_l[seg_l[SKB(HALO + lt)]];
    float x1 = in_l[SK(HALO + i1)]     * dist_l[seg_l[SKB(HALO + i1)]];
    float x2 = in_l[SK(HALO + i1 - 1)] * dist_l[seg_l[SKB(HALO + i1 - 1)]];
    return x0 - (1.0f - alfa) * x1 - alfa * x2;   // in_l is zero-filled for global<0
}

__device__ __forceinline__ void carry_in(const float* __restrict__ in_l,
                                         const unsigned char* __restrict__ seg_l,
                                         const float* __restrict__ dist_l,
                                         const float* __restrict__ f0_l,
                                         const float* __restrict__ f0r,
                                         const float* __restrict__ coefrow,
                                         int base, int t0, float& xm1, float& xm2) {
    xm1 = 0.0f; xm2 = 0.0f;
    int lt = t0 - 1;
    if (base + lt >= 0) {
        int s = seg_l[SKB(HALO + lt)];
        float f0v = (lt >= 0) ? f0_l[SK(lt)] : f0r[base + lt];
        xm1 = comb_lds(in_l, seg_l, dist_l, f0v, coefrow[(s << 3) + 1], lt);
    }
    lt = t0 - 2;
    if (base + lt >= 0) {
        int s = seg_l[SKB(HALO + lt)];
        float f0v = (lt >= 0) ? f0_l[SK(lt)] : f0r[base + lt];
        xm2 = comb_lds(in_l, seg_l, dist_l, f0v, coefrow[(s << 3) + 1], lt);
    }
}

// ---------- K2: per-chunk affine + fused in-wave prefix scan (64-chunk groups) ----------
__global__ __launch_bounds__(256) void k_phase1(const unsigned char* __restrict__ seg,
                                                const float* __restrict__ coef,
                                                const float* __restrict__ f0,
                                                const float* __restrict__ input,
                                                float* __restrict__ AxP,  // [6][NCHUNKS]
                                                float* __restrict__ G) {  // [6][NGROUPS]
    __shared__ float in_l[2576];            // SK(HALO+SPB-1)+1
    __shared__ float f0_l[2112];            // SK(SPB-1)+1
    __shared__ unsigned char seg_l[2656];   // SKB(HALO+SPB-1)+1
    __shared__ float dist_l[256];
    const int blk = blockIdx.x, tid = threadIdx.x;
    const int row = blk >> 5;
    const int base = (blk & 31) * SPB;
    const float* inr = input + (size_t)row * TT;
    const float* f0r = f0 + (size_t)row * TT;
    const unsigned char* segr = seg + (size_t)row * TT;
    const float* coefrow = coef + ((size_t)row << 11);

    for (int i = tid; i < HALO + SPB; i += 256) {
        int g = base - HALO + i;
        in_l[SK(i)]   = (g >= 0) ? inr[g] : 0.0f;
        seg_l[SKB(i)] = (g >= 0) ? segr[g] : (unsigned char)0;
    }
    for (int i = tid; i < SPB; i += 256) f0_l[SK(i)] = f0r[base + i];
    dist_l[tid] = coefrow[tid << 3];
    __syncthreads();

    const int t0 = tid * CHUNK;
    float xm1, xm2;
    carry_in(in_l, seg_l, dist_l, f0_l, f0r, coefrow, base, t0, xm1, xm2);

    int scur = -1;
    float mu = 0, b0 = 0, b1 = 0, ca1 = 0, ca2 = 0;
    float a00 = 1, a01 = 0, a10 = 0, a11 = 1, d0 = 0, d1 = 0;
    #pragma unroll
    for (int j = 0; j < CHUNK; ++j) {
        int lt = t0 + j;
        int s = seg_l[SKB(HALO + lt)];
        if (s != scur) {
            const float4* c4 = (const float4*)(coefrow + (s << 3));
            float4 c0 = c4[0], c1 = c4[1];
            mu = c0.y; b0 = c0.z; b1 = c0.w; ca1 = c1.x; ca2 = c1.y; scur = s;
        }
        float xc = comb_lds(in_l, seg_l, dist_l, f0_l[SK(lt)], mu, lt);
        float f = b0 * xc + b1 * xm1 + b0 * xm2;
        xm2 = xm1; xm1 = xc;
        float n00 = -ca1 * a00 - ca2 * a10;
        float n01 = -ca1 * a01 - ca2 * a11;
        float nd0 = f - ca1 * d0 - ca2 * d1;
        a10 = a00; a11 = a01; d1 = d0;
        a00 = n00; a01 = n01; d0 = nd0;
    }
    // in-wave inclusive compose scan (prefix = own ∘ earlier)
    int lane = tid & 63;
    for (int off = 1; off < 64; off <<= 1) {
        float p00 = __shfl_up(a00, off), p01 = __shfl_up(a01, off);
        float p10 = __shfl_up(a10, off), p11 = __shfl_up(a11, off);
        float pd0 = __shfl_up(d0, off),  pd1 = __shfl_up(d1, off);
        if (lane >= off) {
            float n00 = a00 * p00 + a01 * p10, n01 = a00 * p01 + a01 * p11;
            float n10 = a10 * p00 + a11 * p10, n11 = a10 * p01 + a11 * p11;
            float nd0 = a00 * pd0 + a01 * pd1 + d0, nd1 = a10 * pd0 + a11 * pd1 + d1;
            a00 = n00; a01 = n01; a10 = n10; a11 = n11; d0 = nd0; d1 = nd1;
        }
    }
    int chunkid = blk * 256 + tid;
    AxP[0 * NCHUNKS + chunkid] = a00; AxP[1 * NCHUNKS + chunkid] = a01;
    AxP[2 * NCHUNKS + chunkid] = a10; AxP[3 * NCHUNKS + chunkid] = a11;
    AxP[4 * NCHUNKS + chunkid] = d0;  AxP[5 * NCHUNKS + chunkid] = d1;
    if (lane == 63) {
        int gi = chunkid >> 6;
        G[0 * NGROUPS + gi] = a00; G[1 * NGROUPS + gi] = a01; G[2 * NGROUPS + gi] = a10;
        G[3 * NGROUPS + gi] = a11; G[4 * NGROUPS + gi] = d0;  G[5 * NGROUPS + gi] = d1;
    }
}

// ---------- K3: per-row scan of 128 group totals -> group entering states ----------
__global__ __launch_bounds__(64) void k_scanL2(const float* __restrict__ G,
                                               float* __restrict__ gst0,
                                               float* __restrict__ gst1) {
    int r = blockIdx.x, l = threadIdx.x;
    float c00 = 1, c01 = 0, c10 = 0, c11 = 1, cd0 = 0, cd1 = 0;  // carry (identity)
    for (int b2 = 0; b2 < 2; ++b2) {
        int gi = r * 128 + b2 * 64 + l;
        float a00 = G[0 * NGROUPS + gi], a01 = G[1 * NGROUPS + gi];
        float a10 = G[2 * NGROUPS + gi], a11 = G[3 * NGROUPS + gi];
        float d0  = G[4 * NGROUPS + gi], d1  = G[5 * NGROUPS + gi];
        for (int off = 1; off < 64; off <<= 1) {
            float p00 = __shfl_up(a00, off), p01 = __shfl_up(a01, off);
            float p10 = __shfl_up(a10, off), p11 = __shfl_up(a11, off);
            float pd0 = __shfl_up(d0, off),  pd1 = __shfl_up(d1, off);
            if (l >= off) {
                float n00 = a00 * p00 + a01 * p10, n01 = a00 * p01 + a01 * p11;
                float n10 = a10 * p00 + a11 * p10, n11 = a10 * p01 + a11 * p11;
                float nd0 = a00 * pd0 + a01 * pd1 + d0, nd1 = a10 * pd0 + a11 * pd1 + d1;
                a00 = n00; a01 = n01; a10 = n10; a11 = n11; d0 = nd0; d1 = nd1;
            }
        }
        // full = P ∘ carry
        float f00 = a00 * c00 + a01 * c10, f01 = a00 * c01 + a01 * c11;
        float f10 = a10 * c00 + a11 * c10, f11 = a10 * c01 + a11 * c11;
        float fd0 = a00 * cd0 + a01 * cd1 + d0, fd1 = a10 * cd0 + a11 * cd1 + d1;
        float e0 = __shfl_up(fd0, 1), e1 = __shfl_up(fd1, 1);
        if (l == 0) { e0 = cd0; e1 = cd1; }
        gst0[gi] = e0; gst1[gi] = e1;      // state entering group gi (init state = 0)
        c00 = __shfl(f00, 63); c01 = __shfl(f01, 63); c10 = __shfl(f10, 63);
        c11 = __shfl(f11, 63); cd0 = __shfl(fd0, 63); cd1 = __shfl(fd1, 63);
    }
}

// ---------- K4: re-run recurrence per chunk with exact entering state, write y ----------
__global__ __launch_bounds__(256) void k_phase2(const unsigned char* __restrict__ seg,
                                                const float* __restrict__ coef,
                                                const float* __restrict__ f0,
                                                const float* __restrict__ input,
                                                const float* __restrict__ AxP,
                                                const float* __restrict__ gst0,
                                                const float* __restrict__ gst1,
                                                float* __restrict__ out) {
    __shared__ float in_l[2576];
    __shared__ float f0_l[2112];
    __shared__ unsigned char seg_l[2656];
    __shared__ float dist_l[256];
    const int blk = blockIdx.x, tid = threadIdx.x;
    const int row = blk >> 5;
    const int base = (blk & 31) * SPB;
    const float* inr = input + (size_t)row * TT;
    const float* f0r = f0 + (size_t)row * TT;
    const unsigned char* segr = seg + (size_t)row * TT;
    const float* coefrow = coef + ((size_t)row << 11);

    for (int i = tid; i < HALO + SPB; i += 256) {
        int g = base - HALO + i;
        in_l[SK(i)]   = (g >= 0) ? inr[g] : 0.0f;
        seg_l[SKB(i)] = (g >= 0) ? segr[g] : (unsigned char)0;
    }
    for (int i = tid; i < SPB; i += 256) f0_l[SK(i)] = f0r[base + i];
    dist_l[tid] = coefrow[tid << 3];
    __syncthreads();

    const int t0 = tid * CHUNK;
    float xm1, xm2;
    carry_in(in_l, seg_l, dist_l, f0_l, f0r, coefrow, base, t0, xm1, xm2);
    __syncthreads();   // carry-ins read neighbors' f0_l slots; main loop overwrites them

    int chunkid = blk * 256 + tid;
    int lane = tid & 63;
    float g0v = gst0[chunkid >> 6], g1v = gst1[chunkid >> 6];
    float y1, y2;
    if (lane == 0) { y1 = g0v; y2 = g1v; }
    else {
        int q = chunkid - 1;   // within-group inclusive prefix ending just before this chunk
        float q00 = AxP[0 * NCHUNKS + q], q01 = AxP[1 * NCHUNKS + q];
        float q10 = AxP[2 * NCHUNKS + q], q11 = AxP[3 * NCHUNKS + q];
        float qd0 = AxP[4 * NCHUNKS + q], qd1 = AxP[5 * NCHUNKS + q];
        y1 = q00 * g0v + q01 * g1v + qd0;
        y2 = q10 * g0v + q11 * g1v + qd1;
    }

    int scur = -1;
    float mu = 0, b0 = 0, b1 = 0, ca1 = 0, ca2 = 0;
    #pragma unroll
    for (int j = 0; j < CHUNK; ++j) {
        int lt = t0 + j;
        int s = seg_l[SKB(HALO + lt)];
        if (s != scur) {
            const float4* c4 = (const float4*)(coefrow + (s << 3));
            float4 c0 = c4[0], c1 = c4[1];
            mu = c0.y; b0 = c0.z; b1 = c0.w; ca1 = c1.x; ca2 = c1.y; scur = s;
        }
        float f0v = f0_l[SK(lt)];
        float xc = comb_lds(in_l, seg_l, dist_l, f0v, mu, lt);
        float f = b0 * xc + b1 * xm1 + b0 * xm2;
        xm2 = xm1; xm1 = xc;
        float y = f - ca1 * y1 - ca2 * y2;
        y2 = y1; y1 = y;
        f0_l[SK(lt)] = y;      // owner-only slot; safe after the barrier above
    }
    __syncthreads();
    float* outr = out + (size_t)row * TT + base;
    for (int i = tid; i < SPB; i += 256) outr[i] = f0_l[SK(i)];   // coalesced
}

extern "C" void kernel_launch(void* const* d_in, const int* in_sizes, int n_in,
                              void* d_out, int out_size, void* d_ws, size_t ws_size,
                              hipStream_t stream) {
    const float* f0     = (const float*)d_in[0];
    const float* input  = (const float*)d_in[1];
    const float* params = (const float*)d_in[2];
    const int*   onsets = (const int*)d_in[3];
    float* out = (float*)d_out;

    // workspace layout (bytes); total ~9.0 MB (proven available: >=13.27 MB)
    char* ws = (char*)d_ws;
    float*         sums = (float*)(ws + 0);          // 131072  [32][256][4]
    float*         cnt  = (float*)(ws + 131072);     // 32768   [32][256]
    int*           bsum = (int*)  (ws + 163840);     // 32768   [8192]
    int*           bpre = (int*)  (ws + 196608);     // 32768   [8192]
    float*         coef = (float*)(ws + 229376);     // 262144  [32][256][8]
    unsigned char* seg  = (unsigned char*)(ws + 491520); // 2097152 [32][65536]
    float*         AxP  = (float*)(ws + 2588672);    // 6291456 [6][262144]
    float*         G    = (float*)(ws + 8880128);    // 98304   [6][4096]
    float*         gst0 = (float*)(ws + 8978432);    // 16384   [4096]
    float*         gst1 = (float*)(ws + 8994816);    // 16384   [4096]

    hipMemsetAsync(sums, 0, 163840, stream);         // sums + cnt (atomic bins)

    k_count <<<2048, 256, 0, stream>>>(onsets, bsum);
    k_rowpre<<<BB, 64, 0, stream>>>(bsum, bpre);
    k_assign<<<8192, 256, 0, stream>>>(onsets, params, bpre, seg, sums, cnt);
    k_coefs <<<BB * MAXSEG / 256, 256, 0, stream>>>(sums, cnt, coef);
    k_phase1<<<NBLK, 256, 0, stream>>>(seg, coef, f0, input, AxP, G);
    k_scanL2<<<BB, 64, 0, stream>>>(G, gst0, gst1);
    k_phase2<<<NBLK, 256, 0, stream>>>(seg, coef, f0, input, AxP, gst0, gst1, out);
}

// Round 5
// 133.767 us; speedup vs baseline: 2.2009x; 2.2009x over previous
//
#include <hip/hip_runtime.h>
#include <math.h>

// Problem geometry (fixed by the reference).
#define BB 32
#define TT 65536
#define MAXSEG 256             // onsets/row ~ Binom(65536,5e-4) = 33±6 -> P(>=256) ~ 0
#define CHUNK 8                // samples per scan chunk (1 chunk per thread)
#define SPB 2048               // samples per phase block = 256 threads * CHUNK
#define NBLK (BB * TT / SPB)   // 1024 phase blocks (32 per row)
#define CPR (TT / CHUNK)       // 8192 chunks per row
#define NCHUNKS (BB * CPR)     // 262144
#define NGROUPS (NCHUNKS / 64) // 4096 (64-chunk groups == one wave each)
#define NSB (BB * TT / 256)    // 8192 sample-blocks of 256 samples
#define HALO 448               // comb reach: zi<=399 -> i2 >= t-401; +2 carry-in -> <=403

// map_logspace constants: lo * (hi/lo)^sig = lo * exp(sig*ln(hi/lo))
#define MIN_W_C 0.007853981633974483f  // 2*pi*20/16000
#define LNW 5.991464547107982f         // ln(400)
#define MIN_Q_C 0.5f
#define LNQ 1.3862943611198906f        // ln(4)
#define MIN_D_C 0.1f
#define LND 2.995732273553991f         // ln(20)

__device__ __forceinline__ int SK(int i)  { return i + (i >> 5); }  // float-LDS skew
__device__ __forceinline__ int SKB(int i) { return i + (i >> 4); }  // byte-LDS skew
__device__ __forceinline__ float sigmoidf_(float x) { return 1.0f / (1.0f + expf(-x)); }

// ---------- K1a: per-256-sample-block onset count + param float4 sum ----------
__global__ __launch_bounds__(256) void k_count(const int* __restrict__ onsets,
                                               const float* __restrict__ params,
                                               int* __restrict__ bsum,
                                               float4* __restrict__ psum) {
    int tid = threadIdx.x;
    int gid = blockIdx.x * 256 + tid;                 // thread handles 4 samples
    int4 v = ((const int4*)onsets)[gid];
    int c = v.x + v.y + v.z + v.w;
    const float4* pp = ((const float4*)params) + (size_t)gid * 4;
    float4 p0 = pp[0], p1 = pp[1], p2 = pp[2], p3 = pp[3];
    float sx = p0.x + p1.x + p2.x + p3.x;
    float sy = p0.y + p1.y + p2.y + p3.y;
    float sz = p0.z + p1.z + p2.z + p3.z;
    float sw = p0.w + p1.w + p2.w + p3.w;
    for (int off = 32; off; off >>= 1) {
        c  += __shfl_xor(c, off);
        sx += __shfl_xor(sx, off); sy += __shfl_xor(sy, off);
        sz += __shfl_xor(sz, off); sw += __shfl_xor(sw, off);
    }
    if ((tid & 63) == 0) {
        int sb = blockIdx.x * 4 + (tid >> 6);         // wave covers 256 samples
        bsum[sb] = c;
        psum[sb] = make_float4(sx, sy, sz, sw);
    }
}

// ---------- K1b: per-row exclusive prefixes of block counts and block param sums ----------
__global__ __launch_bounds__(64) void k_rowpre(const int* __restrict__ bsum,
                                               const float4* __restrict__ psum,
                                               int* __restrict__ bpre,
                                               float4* __restrict__ ppre,
                                               float4* __restrict__ rowtot,
                                               int* __restrict__ rown) {
    int r = blockIdx.x, l = threadIdx.x;
    int acc = 0;
    float ax = 0, ay = 0, az = 0, aw = 0;
    for (int g = 0; g < 4; ++g) {
        int sb = r * 256 + g * 64 + l;
        int v = bsum[sb];
        float4 f = psum[sb];
        int x = v;
        float fx = f.x, fy = f.y, fz = f.z, fw = f.w;
        for (int off = 1; off < 64; off <<= 1) {
            int   xy = __shfl_up(x, off);
            float ux = __shfl_up(fx, off), uy = __shfl_up(fy, off);
            float uz = __shfl_up(fz, off), uw = __shfl_up(fw, off);
            if (l >= off) { x += xy; fx += ux; fy += uy; fz += uz; fw += uw; }
        }
        bpre[sb] = acc + x - v;                              // exclusive
        ppre[sb] = make_float4(ax + fx - f.x, ay + fy - f.y,
                               az + fz - f.z, aw + fw - f.w); // exclusive
        acc += __shfl(x, 63);
        ax += __shfl(fx, 63); ay += __shfl(fy, 63);
        az += __shfl(fz, 63); aw += __shfl(fw, 63);
    }
    if (l == 0) { rowtot[r] = make_float4(ax, ay, az, aw); rown[r] = acc; }
}

// ---------- K1c: seg bytes + segment-boundary table (NO atomics) ----------
__global__ __launch_bounds__(256) void k_assign(const int* __restrict__ onsets,
                                                const float* __restrict__ params,
                                                const int* __restrict__ bsum,
                                                const int* __restrict__ bpre,
                                                const float4* __restrict__ ppre,
                                                unsigned char* __restrict__ seg,
                                                int* __restrict__ bndT,     // [BB][256]
                                                float4* __restrict__ bndP) {// [BB][256]
    int blk = blockIdx.x;                 // 8192 blocks = one 256-sample block each
    int tid = threadIdx.x;
    int row = blk >> 8;
    size_t g = ((size_t)blk << 8) + tid;
    int bp = bpre[blk];

    if (bsum[blk] == 0) {                 // ~88% of blocks: uniform segment, done
        seg[g] = (unsigned char)min(bp, MAXSEG - 1);
        return;
    }

    int on = onsets[g];
    float4 pv = ((const float4*)params)[g];
    int lane = tid & 63, w = tid >> 6;

    int x = on;
    float fx = pv.x, fy = pv.y, fz = pv.z, fw = pv.w;
    for (int off = 1; off < 64; off <<= 1) {
        int   xy = __shfl_up(x, off);
        float ux = __shfl_up(fx, off), uy = __shfl_up(fy, off);
        float uz = __shfl_up(fz, off), uw = __shfl_up(fw, off);
        if (lane >= off) { x += xy; fx += ux; fy += uy; fz += uz; fw += uw; }
    }
    __shared__ int wt[4];
    __shared__ float4 wtf[4];
    if (lane == 63) { wt[w] = x; wtf[w] = make_float4(fx, fy, fz, fw); }
    __syncthreads();
    int wadd = 0;
    float cx = 0, cy = 0, cz = 0, cw = 0;
    for (int i = 0; i < w; ++i) {
        wadd += wt[i];
        float4 t = wtf[i];
        cx += t.x; cy += t.y; cz += t.z; cw += t.w;
    }
    int incl = bp + wadd + x;             // inclusive onset cumsum at this sample
    seg[g] = (unsigned char)min(incl, MAXSEG - 1);
    if (on && incl <= MAXSEG - 1) {       // this sample STARTS segment `incl`
        float4 pe = ppre[blk];
        int t_row = ((blk & 255) << 8) + tid;
        bndT[row * 256 + incl] = t_row;
        bndP[row * 256 + incl] = make_float4(pe.x + cx + fx - pv.x,
                                             pe.y + cy + fy - pv.y,
                                             pe.z + cz + fz - pv.z,
                                             pe.w + cw + fw - pv.w);
    }
}

// ---------- K1d: coefficient table from boundary differences ----------
// coef[(r,s)*8] = {dist, mu, b0, b1, ca1, ca2, -, -}
__global__ __launch_bounds__(256) void k_coefs(const int* __restrict__ bndT,
                                               const float4* __restrict__ bndP,
                                               const float4* __restrict__ rowtot,
                                               const int* __restrict__ rown,
                                               float* __restrict__ coef) {
    int s = threadIdx.x, r = blockIdx.x;
    int smax = min(rown[r], MAXSEG - 1);
    int ts; float4 Ps;
    if (s == 0)          { ts = 0;  Ps = make_float4(0, 0, 0, 0); }
    else if (s <= smax)  { ts = bndT[r * 256 + s]; Ps = bndP[r * 256 + s]; }
    else                 { ts = TT; Ps = rowtot[r]; }
    int te; float4 Pe;
    if (s >= smax)       { te = TT; Pe = rowtot[r]; }
    else                 { te = bndT[r * 256 + s + 1]; Pe = bndP[r * 256 + s + 1]; }
    float c = fmaxf((float)(te - ts), 1.0f);
    float p0 = (Pe.x - Ps.x) / c, p1 = (Pe.y - Ps.y) / c;
    float p2 = (Pe.z - Ps.z) / c, p3 = (Pe.w - Ps.w) / c;
    float dist = MIN_D_C * expf(sigmoidf_(p0) * LND);
    float mu   = sigmoidf_(p3);
    float wq   = MIN_W_C * expf(sigmoidf_(p1) * LNW);
    float q    = MIN_Q_C * expf(sigmoidf_(p2) * LNQ);
    float cwv = cosf(wq), sn = sinf(wq);
    float al = sn / (2.0f * q);
    float a0 = 1.0f + al;
    float omc = 1.0f - cwv;
    float b0 = omc * 0.5f / a0;
    float b1 = omc / a0;
    float ca1 = (-2.0f * cwv) / a0;
    float ca2 = (1.0f - al) / a0;
    float4* o = (float4*)(coef + ((size_t)r * 256 + s) * 8);
    o[0] = make_float4(dist, mu, b0, b1);
    o[1] = make_float4(ca1, ca2, 0.0f, 0.0f);
}

// ---------- shared helpers for the phase kernels ----------
// in_l holds PRE-SCALED x (input*dist); comb at local index lt
__device__ __forceinline__ float comb_pre(const float* __restrict__ in_l,
                                          float f0v, float mu, int lt) {
    float p = f0v * mu;                 // in (0, 400)
    int zi = (int)p;
    float alfa = p - (float)zi;
    int i1 = lt - zi - 1;
    float x0 = in_l[SK(HALO + lt)];
    float x1 = in_l[SK(HALO + i1)];
    float x2 = in_l[SK(HALO + i1 - 1)];
    return x0 - (1.0f - alfa) * x1 - alfa * x2;   // zero-filled for global<0
}

__device__ __forceinline__ void carry_in(const float* __restrict__ in_l,
                                         const unsigned char* __restrict__ seg_l,
                                         const float* __restrict__ f0_l,
                                         const float* __restrict__ f0r,
                                         const float* __restrict__ coefrow,
                                         int base, int t0, float& xm1, float& xm2) {
    xm1 = 0.0f; xm2 = 0.0f;
    int lt = t0 - 1;
    if (base + lt >= 0) {
        int s = seg_l[SKB(HALO + lt)];
        float f0v = (lt >= 0) ? f0_l[SK(lt)] : f0r[base + lt];
        xm1 = comb_pre(in_l, f0v, coefrow[(s << 3) + 1], lt);
    }
    lt = t0 - 2;
    if (base + lt >= 0) {
        int s = seg_l[SKB(HALO + lt)];
        float f0v = (lt >= 0) ? f0_l[SK(lt)] : f0r[base + lt];
        xm2 = comb_pre(in_l, f0v, coefrow[(s << 3) + 1], lt);
    }
}

// stage in_l (pre-scaled), seg_l, f0_l for one 2048-sample window
__device__ __forceinline__ void stage_window(const float* __restrict__ inr,
                                             const float* __restrict__ f0r,
                                             const unsigned char* __restrict__ segr,
                                             const float* __restrict__ coefrow,
                                             int base, int tid,
                                             float* in_l, unsigned char* seg_l,
                                             float* f0_l) {
    for (int i = tid; i < HALO + SPB; i += 256) {
        int g = base - HALO + i;
        unsigned char sv = (g >= 0) ? segr[g] : (unsigned char)0;
        seg_l[SKB(i)] = sv;
        in_l[SK(i)] = (g >= 0) ? inr[g] * coefrow[(int)sv << 3] : 0.0f;
    }
    for (int i = tid; i < SPB; i += 256) f0_l[SK(i)] = f0r[base + i];
}

// ---------- K2: per-chunk affine + fused in-wave prefix scan (64-chunk groups) ----------
__global__ __launch_bounds__(256) void k_phase1(const unsigned char* __restrict__ seg,
                                                const float* __restrict__ coef,
                                                const float* __restrict__ f0,
                                                const float* __restrict__ input,
                                                float* __restrict__ AxP,  // [6][NCHUNKS]
                                                float* __restrict__ G) {  // [6][NGROUPS]
    __shared__ float in_l[2576];            // SK(HALO+SPB-1)+1
    __shared__ float f0_l[2112];            // SK(SPB-1)+1
    __shared__ unsigned char seg_l[2656];   // SKB(HALO+SPB-1)+1
    const int blk = blockIdx.x, tid = threadIdx.x;
    const int row = blk >> 5;
    const int base = (blk & 31) * SPB;
    const float* inr = input + (size_t)row * TT;
    const float* f0r = f0 + (size_t)row * TT;
    const unsigned char* segr = seg + (size_t)row * TT;
    const float* coefrow = coef + ((size_t)row << 11);

    stage_window(inr, f0r, segr, coefrow, base, tid, in_l, seg_l, f0_l);
    __syncthreads();

    const int t0 = tid * CHUNK;
    float xm1, xm2;
    carry_in(in_l, seg_l, f0_l, f0r, coefrow, base, t0, xm1, xm2);

    int scur = -1;
    float mu = 0, b0 = 0, b1 = 0, ca1 = 0, ca2 = 0;
    float a00 = 1, a01 = 0, a10 = 0, a11 = 1, d0 = 0, d1 = 0;
    #pragma unroll
    for (int j = 0; j < CHUNK; ++j) {
        int lt = t0 + j;
        int s = seg_l[SKB(HALO + lt)];
        if (s != scur) {
            const float4* c4 = (const float4*)(coefrow + (s << 3));
            float4 c0 = c4[0], c1 = c4[1];
            mu = c0.y; b0 = c0.z; b1 = c0.w; ca1 = c1.x; ca2 = c1.y; scur = s;
        }
        float xc = comb_pre(in_l, f0_l[SK(lt)], mu, lt);
        float f = b0 * xc + b1 * xm1 + b0 * xm2;
        xm2 = xm1; xm1 = xc;
        float n00 = -ca1 * a00 - ca2 * a10;
        float n01 = -ca1 * a01 - ca2 * a11;
        float nd0 = f - ca1 * d0 - ca2 * d1;
        a10 = a00; a11 = a01; d1 = d0;
        a00 = n00; a01 = n01; d0 = nd0;
    }
    // in-wave inclusive compose scan (prefix = own ∘ earlier)
    int lane = tid & 63;
    for (int off = 1; off < 64; off <<= 1) {
        float p00 = __shfl_up(a00, off), p01 = __shfl_up(a01, off);
        float p10 = __shfl_up(a10, off), p11 = __shfl_up(a11, off);
        float pd0 = __shfl_up(d0, off),  pd1 = __shfl_up(d1, off);
        if (lane >= off) {
            float n00 = a00 * p00 + a01 * p10, n01 = a00 * p01 + a01 * p11;
            float n10 = a10 * p00 + a11 * p10, n11 = a10 * p01 + a11 * p11;
            float nd0 = a00 * pd0 + a01 * pd1 + d0, nd1 = a10 * pd0 + a11 * pd1 + d1;
            a00 = n00; a01 = n01; a10 = n10; a11 = n11; d0 = nd0; d1 = nd1;
        }
    }
    int chunkid = blk * 256 + tid;
    AxP[0 * NCHUNKS + chunkid] = a00; AxP[1 * NCHUNKS + chunkid] = a01;
    AxP[2 * NCHUNKS + chunkid] = a10; AxP[3 * NCHUNKS + chunkid] = a11;
    AxP[4 * NCHUNKS + chunkid] = d0;  AxP[5 * NCHUNKS + chunkid] = d1;
    if (lane == 63) {
        int gi = chunkid >> 6;
        G[0 * NGROUPS + gi] = a00; G[1 * NGROUPS + gi] = a01; G[2 * NGROUPS + gi] = a10;
        G[3 * NGROUPS + gi] = a11; G[4 * NGROUPS + gi] = d0;  G[5 * NGROUPS + gi] = d1;
    }
}

// ---------- K3: per-row scan of 128 group totals -> group entering states ----------
__global__ __launch_bounds__(64) void k_scanL2(const float* __restrict__ G,
                                               float* __restrict__ gst0,
                                               float* __restrict__ gst1) {
    int r = blockIdx.x, l = threadIdx.x;
    float c00 = 1, c01 = 0, c10 = 0, c11 = 1, cd0 = 0, cd1 = 0;  // carry (identity)
    for (int b2 = 0; b2 < 2; ++b2) {
        int gi = r * 128 + b2 * 64 + l;
        float a00 = G[0 * NGROUPS + gi], a01 = G[1 * NGROUPS + gi];
        float a10 = G[2 * NGROUPS + gi], a11 = G[3 * NGROUPS + gi];
        float d0  = G[4 * NGROUPS + gi], d1  = G[5 * NGROUPS + gi];
        for (int off = 1; off < 64; off <<= 1) {
            float p00 = __shfl_up(a00, off), p01 = __shfl_up(a01, off);
            float p10 = __shfl_up(a10, off), p11 = __shfl_up(a11, off);
            float pd0 = __shfl_up(d0, off),  pd1 = __shfl_up(d1, off);
            if (l >= off) {
                float n00 = a00 * p00 + a01 * p10, n01 = a00 * p01 + a01 * p11;
                float n10 = a10 * p00 + a11 * p10, n11 = a10 * p01 + a11 * p11;
                float nd0 = a00 * pd0 + a01 * pd1 + d0, nd1 = a10 * pd0 + a11 * pd1 + d1;
                a00 = n00; a01 = n01; a10 = n10; a11 = n11; d0 = nd0; d1 = nd1;
            }
        }
        // full = P ∘ carry
        float f00 = a00 * c00 + a01 * c10, f01 = a00 * c01 + a01 * c11;
        float f10 = a10 * c00 + a11 * c10, f11 = a10 * c01 + a11 * c11;
        float fd0 = a00 * cd0 + a01 * cd1 + d0, fd1 = a10 * cd0 + a11 * cd1 + d1;
        float e0 = __shfl_up(fd0, 1), e1 = __shfl_up(fd1, 1);
        if (l == 0) { e0 = cd0; e1 = cd1; }
        gst0[gi] = e0; gst1[gi] = e1;      // state entering group gi (init state = 0)
        c00 = __shfl(f00, 63); c01 = __shfl(f01, 63); c10 = __shfl(f10, 63);
        c11 = __shfl(f11, 63); cd0 = __shfl(fd0, 63); cd1 = __shfl(fd1, 63);
    }
}

// ---------- K4: re-run recurrence per chunk with exact entering state, write y ----------
__global__ __launch_bounds__(256) void k_phase2(const unsigned char* __restrict__ seg,
                                                const float* __restrict__ coef,
                                                const float* __restrict__ f0,
                                                const float* __restrict__ input,
                                                const float* __restrict__ AxP,
                                                const float* __restrict__ gst0,
                                                const float* __restrict__ gst1,
                                                float* __restrict__ out) {
    __shared__ float in_l[2576];
    __shared__ float f0_l[2112];
    __shared__ unsigned char seg_l[2656];
    const int blk = blockIdx.x, tid = threadIdx.x;
    const int row = blk >> 5;
    const int base = (blk & 31) * SPB;
    const float* inr = input + (size_t)row * TT;
    const float* f0r = f0 + (size_t)row * TT;
    const unsigned char* segr = seg + (size_t)row * TT;
    const float* coefrow = coef + ((size_t)row << 11);

    stage_window(inr, f0r, segr, coefrow, base, tid, in_l, seg_l, f0_l);
    __syncthreads();

    const int t0 = tid * CHUNK;
    float xm1, xm2;
    carry_in(in_l, seg_l, f0_l, f0r, coefrow, base, t0, xm1, xm2);
    __syncthreads();   // carry-ins read neighbors' f0_l slots; main loop overwrites them

    int chunkid = blk * 256 + tid;
    int lane = tid & 63;
    float g0v = gst0[chunkid >> 6], g1v = gst1[chunkid >> 6];
    float y1, y2;
    if (lane == 0) { y1 = g0v; y2 = g1v; }
    else {
        int q = chunkid - 1;   // within-group inclusive prefix ending just before this chunk
        float q00 = AxP[0 * NCHUNKS + q], q01 = AxP[1 * NCHUNKS + q];
        float q10 = AxP[2 * NCHUNKS + q], q11 = AxP[3 * NCHUNKS + q];
        float qd0 = AxP[4 * NCHUNKS + q], qd1 = AxP[5 * NCHUNKS + q];
        y1 = q00 * g0v + q01 * g1v + qd0;
        y2 = q10 * g0v + q11 * g1v + qd1;
    }

    int scur = -1;
    float mu = 0, b0 = 0, b1 = 0, ca1 = 0, ca2 = 0;
    #pragma unroll
    for (int j = 0; j < CHUNK; ++j) {
        int lt = t0 + j;
        int s = seg_l[SKB(HALO + lt)];
        if (s != scur) {
            const float4* c4 = (const float4*)(coefrow + (s << 3));
            float4 c0 = c4[0], c1 = c4[1];
            mu = c0.y; b0 = c0.z; b1 = c0.w; ca1 = c1.x; ca2 = c1.y; scur = s;
        }
        float xc = comb_pre(in_l, f0_l[SK(lt)], mu, lt);
        float f = b0 * xc + b1 * xm1 + b0 * xm2;
        xm2 = xm1; xm1 = xc;
        float y = f - ca1 * y1 - ca2 * y2;
        y2 = y1; y1 = y;
        f0_l[SK(lt)] = y;      // owner-only slot; safe after the barrier above
    }
    __syncthreads();
    float* outr = out + (size_t)row * TT + base;
    for (int i = tid; i < SPB; i += 256) outr[i] = f0_l[SK(i)];   // coalesced
}

extern "C" void kernel_launch(void* const* d_in, const int* in_sizes, int n_in,
                              void* d_out, int out_size, void* d_ws, size_t ws_size,
                              hipStream_t stream) {
    const float* f0     = (const float*)d_in[0];
    const float* input  = (const float*)d_in[1];
    const float* params = (const float*)d_in[2];
    const int*   onsets = (const int*)d_in[3];
    float* out = (float*)d_out;

    // workspace layout (bytes); total ~9.1 MB (proven available: >=13.27 MB)
    char* ws = (char*)d_ws;
    int*           bsum   = (int*)   (ws + 0);        // 32768   [8192]
    int*           bpre   = (int*)   (ws + 32768);    // 32768   [8192]
    float4*        psum   = (float4*)(ws + 65536);    // 131072  [8192]
    float4*        ppre   = (float4*)(ws + 196608);   // 131072  [8192]
    float4*        rowtot = (float4*)(ws + 327680);   // 512     [32]
    int*           rown   = (int*)   (ws + 328192);   // 128     [32]
    int*           bndT   = (int*)   (ws + 328320);   // 32768   [32][256]
    float4*        bndP   = (float4*)(ws + 361088);   // 131072  [32][256]
    float*         coef   = (float*) (ws + 492160);   // 262144  [32][256][8]
    unsigned char* seg    = (unsigned char*)(ws + 754304); // 2097152 [32][65536]
    float*         AxP    = (float*) (ws + 2851456);  // 6291456 [6][262144]
    float*         G      = (float*) (ws + 9142912);  // 98304   [6][4096]
    float*         gst0   = (float*) (ws + 9241216);  // 16384   [4096]
    float*         gst1   = (float*) (ws + 9257600);  // 16384   [4096]

    k_count <<<2048, 256, 0, stream>>>(onsets, params, bsum, psum);
    k_rowpre<<<BB, 64, 0, stream>>>(bsum, psum, bpre, ppre, rowtot, rown);
    k_assign<<<NSB, 256, 0, stream>>>(onsets, params, bsum, bpre, ppre, seg, bndT, bndP);
    k_coefs <<<BB, 256, 0, stream>>>(bndT, bndP, rowtot, rown, coef);
    k_phase1<<<NBLK, 256, 0, stream>>>(seg, coef, f0, input, AxP, G);
    k_scanL2<<<BB, 64, 0, stream>>>(G, gst0, gst1);
    k_phase2<<<NBLK, 256, 0, stream>>>(seg, coef, f0, input, AxP, gst0, gst1, out);
}

// Round 8
// 124.087 us; speedup vs baseline: 2.3725x; 1.0780x over previous
//
#include <hip/hip_runtime.h>
#include <math.h>

// Problem geometry (fixed by the reference).
#define BB 32
#define TT 65536
#define MAXSEG 256             // onsets/row ~ Binom(65536,5e-4) = 33±6 -> P(>=256) ~ 0
#define CHUNK 8                // samples per scan chunk (1 chunk per thread)
#define SPB 2048               // samples per phase block = 256 threads * CHUNK
#define NBLK (BB * TT / SPB)   // 1024 phase blocks (32 per row)
#define NCHUNKS (BB * TT / CHUNK) // 262144
#define NGROUPS (NCHUNKS / 64) // 4096 (64-chunk groups == one wave each)
#define NSB (BB * TT / 256)    // 8192 sample-blocks of 256 samples
#define HALO 448               // comb reach: zi<=399 -> i2 >= t-401; +2 carry-in -> <=403

// map_logspace constants: lo * (hi/lo)^sig = lo * exp(sig*ln(hi/lo))
#define MIN_W_C 0.007853981633974483f  // 2*pi*20/16000
#define LNW 5.991464547107982f         // ln(400)
#define MIN_Q_C 0.5f
#define LNQ 1.3862943611198906f        // ln(4)
#define MIN_D_C 0.1f
#define LND 2.995732273553991f         // ln(20)

__device__ __forceinline__ int SK(int i)  { return i + (i >> 5); }  // float-LDS skew
__device__ __forceinline__ int SKB(int i) { return i + (i >> 4); }  // byte-LDS skew
__device__ __forceinline__ float sigmoidf_(float x) { return 1.0f / (1.0f + expf(-x)); }

// 6-level wave-inclusive compose scan of affine (A 2x2, d 2-vec); prefix = own ∘ earlier
__device__ __forceinline__ void wscan6(int lane, float& a00, float& a01, float& a10,
                                       float& a11, float& d0, float& d1) {
    for (int off = 1; off < 64; off <<= 1) {
        float p00 = __shfl_up(a00, off), p01 = __shfl_up(a01, off);
        float p10 = __shfl_up(a10, off), p11 = __shfl_up(a11, off);
        float pd0 = __shfl_up(d0, off),  pd1 = __shfl_up(d1, off);
        if (lane >= off) {
            float n00 = a00 * p00 + a01 * p10, n01 = a00 * p01 + a01 * p11;
            float n10 = a10 * p00 + a11 * p10, n11 = a10 * p01 + a11 * p11;
            float nd0 = a00 * pd0 + a01 * pd1 + d0, nd1 = a10 * pd0 + a11 * pd1 + d1;
            a00 = n00; a01 = n01; a10 = n10; a11 = n11; d0 = nd0; d1 = nd1;
        }
    }
}

// per-(row,segment) coefficients from boundary differences (verified in r5 k_coefs)
__device__ __forceinline__ void seg_coefs(int s, int row,
                                          const int* __restrict__ bndT,
                                          const float4* __restrict__ bndP,
                                          const float4* __restrict__ rowtot,
                                          const int* __restrict__ rown,
                                          float& dist, float& mu, float& b0, float& b1,
                                          float& ca1, float& ca2) {
    int smax = min(rown[row], MAXSEG - 1);
    int ts; float4 Ps;
    if (s == 0)         { ts = 0;  Ps = make_float4(0, 0, 0, 0); }
    else if (s <= smax) { ts = bndT[row * 256 + s]; Ps = bndP[row * 256 + s]; }
    else                { ts = TT; Ps = rowtot[row]; }
    int te; float4 Pe;
    if (s >= smax)      { te = TT; Pe = rowtot[row]; }
    else                { te = bndT[row * 256 + s + 1]; Pe = bndP[row * 256 + s + 1]; }
    float c = fmaxf((float)(te - ts), 1.0f);
    float p0 = (Pe.x - Ps.x) / c, p1 = (Pe.y - Ps.y) / c;
    float p2 = (Pe.z - Ps.z) / c, p3 = (Pe.w - Ps.w) / c;
    dist = MIN_D_C * expf(sigmoidf_(p0) * LND);
    mu   = sigmoidf_(p3);
    float wq = MIN_W_C * expf(sigmoidf_(p1) * LNW);
    float q  = MIN_Q_C * expf(sigmoidf_(p2) * LNQ);
    float cwv = cosf(wq), sn = sinf(wq);
    float al = sn / (2.0f * q);
    float a0 = 1.0f + al;
    float omc = 1.0f - cwv;
    b0 = omc * 0.5f / a0;
    b1 = omc / a0;
    ca1 = (-2.0f * cwv) / a0;
    ca2 = (1.0f - al) / a0;
}

// ---------- K1: per-256-sample-block onset count + param float4 sum ----------
__global__ __launch_bounds__(256) void k_count(const int* __restrict__ onsets,
                                               const float* __restrict__ params,
                                               int* __restrict__ bsum,
                                               float4* __restrict__ psum) {
    int tid = threadIdx.x;
    int gid = blockIdx.x * 256 + tid;                 // thread handles 4 samples
    int4 v = ((const int4*)onsets)[gid];
    int c = v.x + v.y + v.z + v.w;
    const float4* pp = ((const float4*)params) + (size_t)gid * 4;
    float4 p0 = pp[0], p1 = pp[1], p2 = pp[2], p3 = pp[3];
    float sx = p0.x + p1.x + p2.x + p3.x;
    float sy = p0.y + p1.y + p2.y + p3.y;
    float sz = p0.z + p1.z + p2.z + p3.z;
    float sw = p0.w + p1.w + p2.w + p3.w;
    for (int off = 32; off; off >>= 1) {
        c  += __shfl_xor(c, off);
        sx += __shfl_xor(sx, off); sy += __shfl_xor(sy, off);
        sz += __shfl_xor(sz, off); sw += __shfl_xor(sw, off);
    }
    if ((tid & 63) == 0) {
        int sb = blockIdx.x * 4 + (tid >> 6);         // wave covers 256 samples
        bsum[sb] = c;
        psum[sb] = make_float4(sx, sy, sz, sw);
    }
}

// ---------- K2: per-row exclusive prefixes of block counts and block param sums ----------
__global__ __launch_bounds__(64) void k_rowpre(const int* __restrict__ bsum,
                                               const float4* __restrict__ psum,
                                               int* __restrict__ bpre,
                                               float4* __restrict__ ppre,
                                               float4* __restrict__ rowtot,
                                               int* __restrict__ rown) {
    int r = blockIdx.x, l = threadIdx.x;
    int acc = 0;
    float ax = 0, ay = 0, az = 0, aw = 0;
    for (int g = 0; g < 4; ++g) {
        int sb = r * 256 + g * 64 + l;
        int v = bsum[sb];
        float4 f = psum[sb];
        int x = v;
        float fx = f.x, fy = f.y, fz = f.z, fw = f.w;
        for (int off = 1; off < 64; off <<= 1) {
            int   xy = __shfl_up(x, off);
            float ux = __shfl_up(fx, off), uy = __shfl_up(fy, off);
            float uz = __shfl_up(fz, off), uw = __shfl_up(fw, off);
            if (l >= off) { x += xy; fx += ux; fy += uy; fz += uz; fw += uw; }
        }
        bpre[sb] = acc + x - v;                              // exclusive
        ppre[sb] = make_float4(ax + fx - f.x, ay + fy - f.y,
                               az + fz - f.z, aw + fw - f.w); // exclusive
        acc += __shfl(x, 63);
        ax += __shfl(fx, 63); ay += __shfl(fy, 63);
        az += __shfl(fz, 63); aw += __shfl(fw, 63);
    }
    if (l == 0) { rowtot[r] = make_float4(ax, ay, az, aw); rown[r] = acc; }
}

// ---------- K3: seg bytes + segment-boundary table (NO atomics) ----------
__global__ __launch_bounds__(256) void k_assign(const int* __restrict__ onsets,
                                                const float* __restrict__ params,
                                                const int* __restrict__ bsum,
                                                const int* __restrict__ bpre,
                                                const float4* __restrict__ ppre,
                                                unsigned char* __restrict__ seg,
                                                int* __restrict__ bndT,     // [BB][256]
                                                float4* __restrict__ bndP) {// [BB][256]
    int blk = blockIdx.x;                 // 8192 blocks = one 256-sample block each
    int tid = threadIdx.x;
    int row = blk >> 8;
    size_t g = ((size_t)blk << 8) + tid;
    int bp = bpre[blk];

    if (bsum[blk] == 0) {                 // ~88% of blocks: uniform segment, done
        seg[g] = (unsigned char)min(bp, MAXSEG - 1);
        return;
    }

    int on = onsets[g];
    float4 pv = ((const float4*)params)[g];
    int lane = tid & 63, w = tid >> 6;

    int x = on;
    float fx = pv.x, fy = pv.y, fz = pv.z, fw = pv.w;
    for (int off = 1; off < 64; off <<= 1) {
        int   xy = __shfl_up(x, off);
        float ux = __shfl_up(fx, off), uy = __shfl_up(fy, off);
        float uz = __shfl_up(fz, off), uw = __shfl_up(fw, off);
        if (lane >= off) { x += xy; fx += ux; fy += uy; fz += uz; fw += uw; }
    }
    __shared__ int wt[4];
    __shared__ float4 wtf[4];
    if (lane == 63) { wt[w] = x; wtf[w] = make_float4(fx, fy, fz, fw); }
    __syncthreads();
    int wadd = 0;
    float cx = 0, cy = 0, cz = 0, cw = 0;
    for (int i = 0; i < w; ++i) {
        wadd += wt[i];
        float4 t = wtf[i];
        cx += t.x; cy += t.y; cz += t.z; cw += t.w;
    }
    int incl = bp + wadd + x;             // inclusive onset cumsum at this sample
    seg[g] = (unsigned char)min(incl, MAXSEG - 1);
    if (on && incl <= MAXSEG - 1) {       // this sample STARTS segment `incl`
        float4 pe = ppre[blk];
        int t_row = ((blk & 255) << 8) + tid;
        bndT[row * 256 + incl] = t_row;
        bndP[row * 256 + incl] = make_float4(pe.x + cx + fx - pv.x,
                                             pe.y + cy + fy - pv.y,
                                             pe.z + cz + fz - pv.z,
                                             pe.w + cw + fw - pv.w);
    }
}

// comb at local index lt; in_l holds PRE-SCALED x (input*dist), zero-filled for global<0
__device__ __forceinline__ float comb_pre(const float* __restrict__ in_l,
                                          float f0v, float mu, int lt) {
    float p = f0v * mu;                 // in (0, 400)
    int zi = (int)p;
    float alfa = p - (float)zi;
    int i1 = lt - zi - 1;
    float x0 = in_l[SK(HALO + lt)];
    float x1 = in_l[SK(HALO + i1)];
    float x2 = in_l[SK(HALO + i1 - 1)];
    return x0 - (1.0f - alfa) * x1 - alfa * x2;
}

// ---------- K4: coefs(+LDS) + comb + f-store + per-chunk affine + in-wave scan ----------
__global__ __launch_bounds__(256) void k_phase1(const unsigned char* __restrict__ seg,
                                                const int* __restrict__ bndT,
                                                const float4* __restrict__ bndP,
                                                const float4* __restrict__ rowtot,
                                                const int* __restrict__ rown,
                                                const float* __restrict__ f0,
                                                const float* __restrict__ input,
                                                float* __restrict__ fglob,
                                                float* __restrict__ AxP,  // [6][NCHUNKS]
                                                float* __restrict__ G) {  // [6][NGROUPS]
    __shared__ float in_l[2576];            // SK(HALO+SPB-1)+1
    __shared__ unsigned char seg_l[2656];   // SKB(HALO+SPB-1)+1
    __shared__ float4 coefA[256];           // {dist, mu, b0, b1}
    __shared__ float2 coefB[256];           // {ca1, ca2}
    const int blk = blockIdx.x, tid = threadIdx.x;
    const int row = blk >> 5;
    const int base = (blk & 31) * SPB;
    const int wstart = base - HALO;         // multiple of 4 (448, 2048 both x4)
    const float* inr = input + (size_t)row * TT;
    const float* f0r = f0 + (size_t)row * TT;
    const unsigned char* segr = seg + (size_t)row * TT;

    {   // coefficient fold: one segment per thread
        float dist, mu, b0, b1, ca1, ca2;
        seg_coefs(tid, row, bndT, bndP, rowtot, rown, dist, mu, b0, b1, ca1, ca2);
        coefA[tid] = make_float4(dist, mu, b0, b1);
        coefB[tid] = make_float2(ca1, ca2);
    }
    for (int i = tid; i < HALO + SPB; i += 256) {
        int g = wstart + i;
        seg_l[SKB(i)] = (g >= 0) ? segr[g] : (unsigned char)0;
    }
    __syncthreads();
    // stage in_l pre-scaled, float4 global loads (aligned: wstart % 4 == 0)
    for (int q = tid; q < (HALO + SPB) / 4; q += 256) {
        int g4 = wstart + q * 4;            // all 4 lanes same sign (halo is x4 aligned)
        float4 v = (g4 >= 0) ? *(const float4*)(inr + g4) : make_float4(0, 0, 0, 0);
        in_l[SK(q * 4 + 0)] = v.x * coefA[seg_l[SKB(q * 4 + 0)]].x;
        in_l[SK(q * 4 + 1)] = v.y * coefA[seg_l[SKB(q * 4 + 1)]].x;
        in_l[SK(q * 4 + 2)] = v.z * coefA[seg_l[SKB(q * 4 + 2)]].x;
        in_l[SK(q * 4 + 3)] = v.w * coefA[seg_l[SKB(q * 4 + 3)]].x;
    }
    __syncthreads();

    const int t0 = tid * CHUNK;
    // own f0 straight to registers (coalesced float4)
    float f0v[8];
    {
        const float4* f4 = (const float4*)(f0r + base);
        float4 A = f4[tid * 2], B = f4[tid * 2 + 1];
        f0v[0] = A.x; f0v[1] = A.y; f0v[2] = A.z; f0v[3] = A.w;
        f0v[4] = B.x; f0v[5] = B.y; f0v[6] = B.z; f0v[7] = B.w;
    }
    // comb history entering the chunk (reads in_l/seg_l only; f0 via 2 scalar loads)
    float xm1 = 0.0f, xm2 = 0.0f;
    {
        int lt = t0 - 1;
        if (base + lt >= 0) {
            int s = seg_l[SKB(HALO + lt)];
            xm1 = comb_pre(in_l, f0r[base + lt], coefA[s].y, lt);
        }
        lt = t0 - 2;
        if (base + lt >= 0) {
            int s = seg_l[SKB(HALO + lt)];
            xm2 = comb_pre(in_l, f0r[base + lt], coefA[s].y, lt);
        }
    }

    int scur = -1;
    float mu = 0, b0 = 0, b1 = 0, ca1 = 0, ca2 = 0;
    float a00 = 1, a01 = 0, a10 = 0, a11 = 1, d0 = 0, d1 = 0;
    float fv[8];
    #pragma unroll
    for (int j = 0; j < CHUNK; ++j) {
        int lt = t0 + j;
        int s = seg_l[SKB(HALO + lt)];
        if (s != scur) {
            float4 cA = coefA[s]; float2 cB = coefB[s];
            mu = cA.y; b0 = cA.z; b1 = cA.w; ca1 = cB.x; ca2 = cB.y; scur = s;
        }
        float xc = comb_pre(in_l, f0v[j], mu, lt);
        float f = b0 * xc + b1 * xm1 + b0 * xm2;
        xm2 = xm1; xm1 = xc;
        fv[j] = f;
        float n00 = -ca1 * a00 - ca2 * a10;
        float n01 = -ca1 * a01 - ca2 * a11;
        float nd0 = f - ca1 * d0 - ca2 * d1;
        a10 = a00; a11 = a01; d1 = d0;
        a00 = n00; a01 = n01; d0 = nd0;
    }
    // f out (coalesced float4; phase2 consumes)
    {
        float4* fr4 = (float4*)(fglob + (size_t)row * TT + base);
        fr4[tid * 2]     = make_float4(fv[0], fv[1], fv[2], fv[3]);
        fr4[tid * 2 + 1] = make_float4(fv[4], fv[5], fv[6], fv[7]);
    }
    int lane = tid & 63;
    wscan6(lane, a00, a01, a10, a11, d0, d1);
    int chunkid = blk * 256 + tid;
    AxP[0 * NCHUNKS + chunkid] = a00; AxP[1 * NCHUNKS + chunkid] = a01;
    AxP[2 * NCHUNKS + chunkid] = a10; AxP[3 * NCHUNKS + chunkid] = a11;
    AxP[4 * NCHUNKS + chunkid] = d0;  AxP[5 * NCHUNKS + chunkid] = d1;
    if (lane == 63) {
        int gi = chunkid >> 6;
        G[0 * NGROUPS + gi] = a00; G[1 * NGROUPS + gi] = a01; G[2 * NGROUPS + gi] = a10;
        G[3 * NGROUPS + gi] = a11; G[4 * NGROUPS + gi] = d0;  G[5 * NGROUPS + gi] = d1;
    }
}

// ---------- K5: fused L2-scan + per-chunk recurrence on stored f, write y ----------
__global__ __launch_bounds__(256) void k_phase2(const unsigned char* __restrict__ seg,
                                                const int* __restrict__ bndT,
                                                const float4* __restrict__ bndP,
                                                const float4* __restrict__ rowtot,
                                                const int* __restrict__ rown,
                                                const float* __restrict__ fglob,
                                                const float* __restrict__ AxP,
                                                const float* __restrict__ G,
                                                float* __restrict__ out) {
    __shared__ float2 ca_l[256];
    const int blk = blockIdx.x, tid = threadIdx.x;
    const int row = blk >> 5;
    const int base = (blk & 31) * SPB;

    {   // ca-only coefficient fold
        float dist, mu, b0, b1, ca1, ca2;
        seg_coefs(tid, row, bndT, bndP, rowtot, rown, dist, mu, b0, b1, ca1, ca2);
        ca_l[tid] = make_float2(ca1, ca2);
    }
    __syncthreads();

    const int t0 = tid * CHUNK;
    // own f + seg bytes (coalesced: per-thread-contiguous float4/uint2 across wave)
    float fv[8];
    {
        const float4* f4 = (const float4*)(fglob + (size_t)row * TT + base);
        float4 A = f4[tid * 2], B = f4[tid * 2 + 1];
        fv[0] = A.x; fv[1] = A.y; fv[2] = A.z; fv[3] = A.w;
        fv[4] = B.x; fv[5] = B.y; fv[6] = B.z; fv[7] = B.w;
    }
    uint2 sv = *(const uint2*)(seg + (size_t)row * TT + base + t0);

    // fused scanL2: each wave scans its row's 128 group affines, extracts own prefix
    int lane = tid & 63, wv = tid >> 6;
    int gown = (blk & 31) * 4 + wv;       // own group index within row (== own wave)
    int gb = row * 128;
    float a00 = G[0 * NGROUPS + gb + lane], a01 = G[1 * NGROUPS + gb + lane];
    float a10 = G[2 * NGROUPS + gb + lane], a11 = G[3 * NGROUPS + gb + lane];
    float d0  = G[4 * NGROUPS + gb + lane], d1  = G[5 * NGROUPS + gb + lane];
    wscan6(lane, a00, a01, a10, a11, d0, d1);
    float r0d0 = d0, r0d1 = d1;
    float c00 = __shfl(a00, 63), c01 = __shfl(a01, 63);
    float c10 = __shfl(a10, 63), c11 = __shfl(a11, 63);
    float cd0 = __shfl(d0, 63),  cd1 = __shfl(d1, 63);
    float e0, e1;
    if (gown == 0) { e0 = 0.0f; e1 = 0.0f; }
    else if (gown <= 64) {
        e0 = __shfl(r0d0, gown - 1); e1 = __shfl(r0d1, gown - 1);
    } else {
        float b00 = G[0 * NGROUPS + gb + 64 + lane], b01 = G[1 * NGROUPS + gb + 64 + lane];
        float b10 = G[2 * NGROUPS + gb + 64 + lane], b11 = G[3 * NGROUPS + gb + 64 + lane];
        float e0v = G[4 * NGROUPS + gb + 64 + lane], e1v = G[5 * NGROUPS + gb + 64 + lane];
        wscan6(lane, b00, b01, b10, b11, e0v, e1v);
        float fd0 = b00 * cd0 + b01 * cd1 + e0v;   // compose round-1 prefix with carry
        float fd1 = b10 * cd0 + b11 * cd1 + e1v;
        e0 = __shfl(fd0, gown - 65); e1 = __shfl(fd1, gown - 65);
    }

    // chunk entering state: gst composed with within-group inclusive prefix
    int chunkid = blk * 256 + tid;
    float y1, y2;
    if (lane == 0) { y1 = e0; y2 = e1; }
    else {
        int q = chunkid - 1;
        float q00 = AxP[0 * NCHUNKS + q], q01 = AxP[1 * NCHUNKS + q];
        float q10 = AxP[2 * NCHUNKS + q], q11 = AxP[3 * NCHUNKS + q];
        float qd0 = AxP[4 * NCHUNKS + q], qd1 = AxP[5 * NCHUNKS + q];
        y1 = q00 * e0 + q01 * e1 + qd0;
        y2 = q10 * e0 + q11 * e1 + qd1;
    }

    int scur = -1;
    float ca1 = 0, ca2 = 0;
    float ov[8];
    #pragma unroll
    for (int j = 0; j < CHUNK; ++j) {
        int s = (int)((j < 4 ? (sv.x >> (8 * j)) : (sv.y >> (8 * (j - 4)))) & 255u);
        if (s != scur) { float2 c = ca_l[s]; ca1 = c.x; ca2 = c.y; scur = s; }
        float y = fv[j] - ca1 * y1 - ca2 * y2;
        y2 = y1; y1 = y;
        ov[j] = y;
    }
    float4* o4 = (float4*)(out + (size_t)row * TT + base);
    o4[tid * 2]     = make_float4(ov[0], ov[1], ov[2], ov[3]);
    o4[tid * 2 + 1] = make_float4(ov[4], ov[5], ov[6], ov[7]);
}

extern "C" void kernel_launch(void* const* d_in, const int* in_sizes, int n_in,
                              void* d_out, int out_size, void* d_ws, size_t ws_size,
                              hipStream_t stream) {
    const float* f0     = (const float*)d_in[0];
    const float* input  = (const float*)d_in[1];
    const float* params = (const float*)d_in[2];
    const int*   onsets = (const int*)d_in[3];
    float* out = (float*)d_out;

    // workspace layout (bytes); total ~17.4 MB
    char* ws = (char*)d_ws;
    int*           bsum   = (int*)   (ws + 0);        // 32768   [8192]
    int*           bpre   = (int*)   (ws + 32768);    // 32768   [8192]
    float4*        psum   = (float4*)(ws + 65536);    // 131072  [8192]
    float4*        ppre   = (float4*)(ws + 196608);   // 131072  [8192]
    float4*        rowtot = (float4*)(ws + 327680);   // 512     [32]
    int*           rown   = (int*)   (ws + 328192);   // 128     [32]
    int*           bndT   = (int*)   (ws + 328320);   // 32768   [32][256]
    float4*        bndP   = (float4*)(ws + 361088);   // 131072  [32][256]
    unsigned char* seg    = (unsigned char*)(ws + 492160); // 2097152 [32][65536]
    float*         AxP    = (float*) (ws + 2589312);  // 6291456 [6][262144]
    float*         G      = (float*) (ws + 8880768);  // 98304   [6][4096]
    float*         fglob  = (float*) (ws + 8979072);  // 8388608 [32][65536]

    k_count <<<2048, 256, 0, stream>>>(onsets, params, bsum, psum);
    k_rowpre<<<BB, 64, 0, stream>>>(bsum, psum, bpre, ppre, rowtot, rown);
    k_assign<<<NSB, 256, 0, stream>>>(onsets, params, bsum, bpre, ppre, seg, bndT, bndP);
    k_phase1<<<NBLK, 256, 0, stream>>>(seg, bndT, bndP, rowtot, rown, f0, input,
                                       fglob, AxP, G);
    k_phase2<<<NBLK, 256, 0, stream>>>(seg, bndT, bndP, rowtot, rown, fglob, AxP, G, out);
}